// Round 1
// 298.505 us; speedup vs baseline: 1.0198x; 1.0198x over previous
//
#include <hip/hip_runtime.h>
#include <stdint.h>

// Q8_0-style dequant + linear. Harness upcasts f16 -> fp32: x/scales/bias are
// const float*, out is float*. q_weight is int32.
//   W[o,k] = (q[o,k]-128) * scales[o,k/32]
//   out[m,o] = sum_k x[m,k]*W[o,k] + bias[o]   (bf16 MFMA, fp32 accum/out)
// M = 4096, N = O = 4096, K = 4096.
//
// R8: port to the 256x256 8-phase schedule (learn_hip m201 template):
//  - BM=BN=256, BK=64, 512 thr (8 waves 2Mx4N), per-wave 128x64 (8x4 frags).
//  - LDS 128 KiB: A/B double-buffered 256x64 bf16 tiles, 1 block/CU.
//  - T2: slot XOR-swizzle (slot ^= row&7) via pre-swizzled global source
//    (global_load_lds writes linearly) + same XOR on ds_read -> conflict-free.
//  - T3/T4: 8 phases per 2 K-tiles, one half-tile staged per phase, counted
//    vmcnt(4) only at phases 4/8 (2 half-tiles stay in flight across barriers).
//  - T5: setprio(1) around each 16-MFMA cluster. T1: XCD swizzle of blockIdx.

#define QOFF 128

typedef __bf16 bf16_t;
typedef __bf16 bf16x8 __attribute__((ext_vector_type(8)));
typedef float f32x4 __attribute__((ext_vector_type(4)));

// s_waitcnt simm16: [3:0] vmcnt lo, [6:4] expcnt(7=none), [11:8] lgkmcnt,
// [15:14] vmcnt hi.
#define W_LGKM0 0xC07F  // lgkmcnt(0) only (vmcnt=63)
#define W_VM4 0x0F74    // vmcnt(4) only (lgkm=15)
#define W_VM0 0x0F70    // vmcnt(0) only

// ---------------------------------------------------------------------------
// Prep: blocks [0, nDeq) dequant q->W (bf16); rest convert x fp32->bf16.
// ---------------------------------------------------------------------------
__global__ __launch_bounds__(256) void prep_kernel(
    const int* __restrict__ q, const float* __restrict__ scales,
    const float* __restrict__ X, bf16_t* __restrict__ W,
    bf16_t* __restrict__ Xb, int K, int NB, int nDeq) {
  const int b = blockIdx.x;
  if (b < nDeq) {
    const size_t e = ((size_t)b * 256 + threadIdx.x) * 8;
    const int o = (int)(e / (size_t)K);
    const int i = (int)(e % (size_t)K);
    const float s = scales[o * NB + (i >> 5)];
    int4 a = *(const int4*)(q + e);
    int4 c = *(const int4*)(q + e + 4);
    const int* av = (const int*)&a;
    const int* cv = (const int*)&c;
    bf16x8 t;
#pragma unroll
    for (int j = 0; j < 4; ++j) t[j] = (bf16_t)((float)(av[j] - QOFF) * s);
#pragma unroll
    for (int j = 0; j < 4; ++j) t[4 + j] = (bf16_t)((float)(cv[j] - QOFF) * s);
    *(bf16x8*)(W + e) = t;
  } else {
    const size_t e = ((size_t)(b - nDeq) * 256 + threadIdx.x) * 8;
    float4 a = *(const float4*)(X + e);
    float4 c = *(const float4*)(X + e + 4);
    bf16x8 t;
    t[0] = (bf16_t)a.x; t[1] = (bf16_t)a.y; t[2] = (bf16_t)a.z; t[3] = (bf16_t)a.w;
    t[4] = (bf16_t)c.x; t[5] = (bf16_t)c.y; t[6] = (bf16_t)c.z; t[7] = (bf16_t)c.w;
    *(bf16x8*)(Xb + e) = t;
  }
}

// ---------------------------------------------------------------------------
__device__ __forceinline__ void async16(bf16_t* lds, const bf16_t* g) {
  __builtin_amdgcn_global_load_lds(
      (const __attribute__((address_space(1))) unsigned int*)(const void*)g,
      (__attribute__((address_space(3))) unsigned int*)(void*)lds, 16, 0, 0);
}

// 16 MFMA: one C-quadrant (4 frag-rows x 2 frag-cols) x K=64 (2 k-subtiles).
// QM/QN compile-time so acc indexing stays in registers (rule #20).
template <int QM, int QN>
__device__ __forceinline__ void mm_block(f32x4 (&acc)[8][4],
                                         const bf16x8 (&af)[4][2],
                                         const bf16x8 (&bv)[2][2]) {
  __builtin_amdgcn_s_setprio(1);
#pragma unroll
  for (int ks = 0; ks < 2; ++ks)
#pragma unroll
    for (int fi = 0; fi < 4; ++fi)
#pragma unroll
      for (int fj = 0; fj < 2; ++fj)
        acc[QM * 4 + fi][QN * 2 + fj] = __builtin_amdgcn_mfma_f32_16x16x32_bf16(
            af[fi][ks], bv[fj][ks], acc[QM * 4 + fi][QN * 2 + fj], 0, 0, 0);
  __builtin_amdgcn_s_setprio(0);
}

// 8 ds_read_b128: A quadrant-row (4 frag-rows x 2 k-subtiles).
__device__ __forceinline__ void rd_a(const bf16_t* base, const int* swz,
                                     bf16x8 (&af)[4][2]) {
#pragma unroll
  for (int fi = 0; fi < 4; ++fi)
#pragma unroll
    for (int ks = 0; ks < 2; ++ks)
      af[fi][ks] = *(const bf16x8*)(base + fi * 1024 + swz[ks]);
}

// 4 ds_read_b128: B quadrant (2 frag-cols x 2 k-subtiles).
__device__ __forceinline__ void rd_b(const bf16_t* base, const int* swz,
                                     bf16x8 (&bv)[2][2]) {
#pragma unroll
  for (int fj = 0; fj < 2; ++fj)
#pragma unroll
    for (int ks = 0; ks < 2; ++ks)
      bv[fj][ks] = *(const bf16x8*)(base + fj * 1024 + swz[ks]);
}

// ---------------------------------------------------------------------------
// 8-phase 256x256 GEMM. Requires M%256==0, N%256==0, K%128==0.
// LDS tile layout (per operand, per buffer): 256 rows x 64 cols bf16, 128-B
// rows of 8 16-B slots; element (row, slot s) stored at slot s^(row&7).
// global_load_lds writes linearly, so the staging global address is
// pre-swizzled with the same XOR (involution, both-sides rule).
// ---------------------------------------------------------------------------
__global__ __launch_bounds__(512, 2) void gemm_8ph(
    const bf16_t* __restrict__ A,   // [M, K] x (bf16)
    const bf16_t* __restrict__ B,   // [N, K] dequantized W (bf16)
    const float* __restrict__ bias, // [N]
    float* __restrict__ C,          // [M, N] fp32
    int M, int N, int K) {
  __shared__ bf16_t lsA[2][256 * 64];  // 32 KiB / buf
  __shared__ bf16_t lsB[2][256 * 64];  // 32 KiB / buf

  const int tid = threadIdx.x;
  const int lane = tid & 63;
  const int wave = tid >> 6;
  const int r = lane & 15;   // frag row (A) / col (B)
  const int qd = lane >> 4;  // k-slot within subtile (in), row-group (C/D)
  const int wm = (wave >> 2) * 128;  // wave-tile m origin
  const int wn = (wave & 3) * 64;    // wave-tile n origin

  // T1: bijective XCD swizzle (nwg % 8 == 0 guaranteed by launcher shapes).
  const int nbx = N >> 8;
  const int nwg = gridDim.x;
  int wg = blockIdx.x;
  if ((nwg & 7) == 0) wg = (wg & 7) * (nwg >> 3) + (wg >> 3);
  const int m0 = (wg / nbx) * 256;
  const int n0 = (wg % nbx) * 256;

  f32x4 acc[8][4] = {};

  // Staging: half-tile = 128 rows x 64 cols = 16 KiB = 2 issues of 512x16B.
  // Thread t covers (row = t/8, slot = t%8) of a 64-row part; source slot is
  // pre-swizzled: s' = (t%8) ^ (row&7).
  const int srow = tid >> 3;                     // 0..63
  const int sslot = (tid & 7) ^ (srow & 7);      // pre-swizzled k-slot
  const bf16_t* gA0 = A + (size_t)(m0 + srow) * K + sslot * 8;
  const bf16_t* gB0 = B + (size_t)(n0 + srow) * K + sslot * 8;

  auto stgA = [&](bf16_t* dstTile, int half, int koff) {
    bf16_t* d = dstTile + half * 8192 + tid * 8;
    const bf16_t* g = gA0 + (size_t)(half * 128) * K + koff;
    async16(d, g);
    async16(d + 4096, g + 64 * (size_t)K);
  };
  auto stgB = [&](bf16_t* dstTile, int half, int koff) {
    bf16_t* d = dstTile + half * 8192 + tid * 8;
    const bf16_t* g = gB0 + (size_t)(half * 128) * K + koff;
    async16(d, g);
    async16(d + 4096, g + 64 * (size_t)K);
  };

  // Per-lane read offsets: elem = row*64 + ((ks*4+qd)^(row&7))*8, row&7==r&7.
  const int swz[2] = {(qd ^ (r & 7)) * 8, ((4 + qd) ^ (r & 7)) * 8};
  const bf16_t* a0base = &lsA[0][(wm + r) * 64];
  const bf16_t* a1base = &lsA[1][(wm + r) * 64];
  const bf16_t* b0base = &lsB[0][(wn + r) * 64];
  const bf16_t* b1base = &lsB[1][(wn + r) * 64];

  const int NT = K >> 6;      // K-tiles (even)
  const int NITER = NT >> 1;  // iterations (2 tiles each)

  // Prologue: tile 0 (buf0, 8 loads) + B of tile 1 (buf1, 4 loads);
  // vmcnt(4) leaves B(1) in flight == steady-state loop entry invariant.
  stgA(lsA[0], 0, 0);
  stgA(lsA[0], 1, 0);
  stgB(lsB[0], 0, 0);
  stgB(lsB[0], 1, 0);
  stgB(lsB[1], 0, 64);
  stgB(lsB[1], 1, 64);
  __builtin_amdgcn_s_waitcnt(W_VM4);
  __builtin_amdgcn_s_barrier();

  bf16x8 af[4][2], bf0[2][2], bf1[2][2];

#pragma unroll 1
  for (int j = 0; j < NITER; ++j) {
    // Stage targets: A(2j+1)->buf1 @P1,P2; B(t2)->buf0 @P3,P4;
    // A(t2)->buf0 @P5,P6; B(t3)->buf1 @P7,P8. Wrapped tiles (last iter) stage
    // valid-but-unread data; parity preserved (NT even).
    const int k1 = (2 * j + 1) * 64;
    int t2 = 2 * j + 2; if (t2 >= NT) t2 -= NT;
    int t3 = 2 * j + 3; if (t3 >= NT) t3 -= NT;
    const int k2 = t2 * 64;
    const int k3 = t3 * 64;

    // ---- P1: tile 2j (buf0), quadrant (0,0). 12 ds_reads.
    rd_a(a0base, swz, af);
    rd_b(b0base, swz, bf0);
    stgA(lsA[1], 0, k1);
    __builtin_amdgcn_s_barrier();
    __builtin_amdgcn_s_waitcnt(W_LGKM0);
    mm_block<0, 0>(acc, af, bf0);
    __builtin_amdgcn_s_barrier();
    // ---- P2: (0,1). 4 ds_reads.
    rd_b(b0base + 2048, swz, bf1);
    stgA(lsA[1], 1, k1);
    __builtin_amdgcn_s_barrier();
    __builtin_amdgcn_s_waitcnt(W_LGKM0);
    mm_block<0, 1>(acc, af, bf1);
    __builtin_amdgcn_s_barrier();
    // ---- P3: (1,1). 8 ds_reads. buf0.B free after P2 -> stage B(t2).
    rd_a(a0base + 4096, swz, af);
    stgB(lsB[0], 0, k2);
    __builtin_amdgcn_s_barrier();
    __builtin_amdgcn_s_waitcnt(W_LGKM0);
    mm_block<1, 1>(acc, af, bf1);
    __builtin_amdgcn_s_barrier();
    // ---- P4: (1,0) reusing bf0. vmcnt(4): tile 2j+1 fully landed, B(t2)
    // stays in flight across the barrier.
    stgB(lsB[0], 1, k2);
    __builtin_amdgcn_s_barrier();
    mm_block<1, 0>(acc, af, bf0);
    __builtin_amdgcn_s_waitcnt(W_VM4);
    __builtin_amdgcn_s_barrier();

    // ---- P5: tile 2j+1 (buf1), (0,0). buf0.A free after P3 -> stage A(t2).
    rd_a(a1base, swz, af);
    rd_b(b1base, swz, bf0);
    stgA(lsA[0], 0, k2);
    __builtin_amdgcn_s_barrier();
    __builtin_amdgcn_s_waitcnt(W_LGKM0);
    mm_block<0, 0>(acc, af, bf0);
    __builtin_amdgcn_s_barrier();
    // ---- P6: (0,1).
    rd_b(b1base + 2048, swz, bf1);
    stgA(lsA[0], 1, k2);
    __builtin_amdgcn_s_barrier();
    __builtin_amdgcn_s_waitcnt(W_LGKM0);
    mm_block<0, 1>(acc, af, bf1);
    __builtin_amdgcn_s_barrier();
    // ---- P7: (1,1). buf1.B free after P6 -> stage B(t3).
    rd_a(a1base + 4096, swz, af);
    stgB(lsB[1], 0, k3);
    __builtin_amdgcn_s_barrier();
    __builtin_amdgcn_s_waitcnt(W_LGKM0);
    mm_block<1, 1>(acc, af, bf1);
    __builtin_amdgcn_s_barrier();
    // ---- P8: (1,0). vmcnt(4): tile t2 fully landed for next-iter P1.
    stgB(lsB[1], 1, k3);
    __builtin_amdgcn_s_barrier();
    mm_block<1, 0>(acc, af, bf0);
    __builtin_amdgcn_s_waitcnt(W_VM4);
    __builtin_amdgcn_s_barrier();
  }

  // Drain wrapped in-flight DMAs before exit (LDS reuse safety).
  __builtin_amdgcn_s_waitcnt(W_VM0);

  // Epilogue: C/D mapping col = lane&15 (n), row = qd*4 + reg (m). fp32 out.
#pragma unroll
  for (int ni = 0; ni < 4; ++ni) {
    const int n = n0 + wn + ni * 16 + r;
    const float bv = bias[n];
#pragma unroll
    for (int mi = 0; mi < 8; ++mi) {
      const int mbase = m0 + wm + mi * 16 + qd * 4;
#pragma unroll
      for (int reg = 0; reg < 4; ++reg) {
        C[(size_t)(mbase + reg) * N + n] = acc[mi][ni][reg] + bv;
      }
    }
  }
}

// ---------------------------------------------------------------------------
// Fallback GEMM (any K%32==0): 128x128 double-buffered version.
// ---------------------------------------------------------------------------
__global__ __launch_bounds__(256) void gemm_db(
    const bf16_t* __restrict__ A, const bf16_t* __restrict__ B,
    const float* __restrict__ bias, float* __restrict__ C, int M, int N,
    int K) {
  __shared__ bf16_t lsA[2][128 * 32];
  __shared__ bf16_t lsB[2][128 * 32];

  const int tid = threadIdx.x;
  const int lane = tid & 63;
  const int wave = tid >> 6;
  const int m0 = blockIdx.y * 128;
  const int n0 = blockIdx.x * 128;
  const int wm = (wave >> 1) * 64;
  const int wn = (wave & 1) * 64;
  const int r = lane & 15;
  const int qd = lane >> 4;

  f32x4 acc[4][4] = {};

  const int e0 = tid * 8;
  const int e1 = 2048 + tid * 8;
  const bf16_t* gA0 = A + (size_t)(m0 + (e0 >> 5)) * K + (e0 & 31);
  const bf16_t* gA1 = A + (size_t)(m0 + (e1 >> 5)) * K + (e1 & 31);
  const bf16_t* gB0 = B + (size_t)(n0 + (e0 >> 5)) * K + (e0 & 31);
  const bf16_t* gB1 = B + (size_t)(n0 + (e1 >> 5)) * K + (e1 & 31);

  async16(&lsA[0][e0], gA0);
  async16(&lsA[0][e1], gA1);
  async16(&lsB[0][e0], gB0);
  async16(&lsB[0][e1], gB1);

  int buf = 0;
  for (int k0 = 0; k0 < K; k0 += 32, buf ^= 1) {
    __syncthreads();
    if (k0 + 32 < K) {
      const int nk = k0 + 32;
      async16(&lsA[buf ^ 1][e0], gA0 + nk);
      async16(&lsA[buf ^ 1][e1], gA1 + nk);
      async16(&lsB[buf ^ 1][e0], gB0 + nk);
      async16(&lsB[buf ^ 1][e1], gB1 + nk);
    }
    bf16x8 af[4], bfv[4];
#pragma unroll
    for (int i = 0; i < 4; ++i) {
      af[i] = *(const bf16x8*)&lsA[buf][(wm + i * 16 + r) * 32 + qd * 8];
      bfv[i] = *(const bf16x8*)&lsB[buf][(wn + i * 16 + r) * 32 + qd * 8];
    }
#pragma unroll
    for (int mi = 0; mi < 4; ++mi)
#pragma unroll
      for (int ni = 0; ni < 4; ++ni)
        acc[mi][ni] = __builtin_amdgcn_mfma_f32_16x16x32_bf16(
            af[mi], bfv[ni], acc[mi][ni], 0, 0, 0);
  }

#pragma unroll
  for (int ni = 0; ni < 4; ++ni) {
    const int n = n0 + wn + ni * 16 + r;
    const float bv = bias[n];
#pragma unroll
    for (int mi = 0; mi < 4; ++mi) {
      const int mbase = m0 + wm + mi * 16 + qd * 4;
#pragma unroll
      for (int reg = 0; reg < 4; ++reg) {
        C[(size_t)(mbase + reg) * N + n] = acc[mi][ni][reg] + bv;
      }
    }
  }
}

// ---------------------------------------------------------------------------
// Fallback (small ws): register-staged GEMM, fused A-convert + B-dequant.
// ---------------------------------------------------------------------------
__global__ __launch_bounds__(256) void gemm_fused(
    const float* __restrict__ Af, const int* __restrict__ q,
    const float* __restrict__ scales, const float* __restrict__ bias,
    float* __restrict__ C, int M, int N, int K, int NB) {
  __shared__ bf16_t lsA[128 * 32];
  __shared__ bf16_t lsB[128 * 32];

  const int tid = threadIdx.x;
  const int lane = tid & 63;
  const int wave = tid >> 6;
  const int m0 = blockIdx.y * 128;
  const int n0 = blockIdx.x * 128;
  const int wm = (wave >> 1) * 64;
  const int wn = (wave & 1) * 64;
  const int r = lane & 15;
  const int qd = lane >> 4;

  const int e = tid * 16;
  const int row = e >> 5;
  const int col = e & 31;

  const float* gAf = Af + (size_t)(m0 + row) * K + col;
  const int* gQ = q + (size_t)(n0 + row) * K + col;
  const float* gS = scales + (size_t)(n0 + row) * NB;

  f32x4 acc[4][4] = {};

  for (int k0 = 0; k0 < K; k0 += 32) {
    bf16x8 a0, a1, b0, b1;
    {
      float4 f0 = *(const float4*)(gAf + k0);
      float4 f1 = *(const float4*)(gAf + k0 + 4);
      float4 f2 = *(const float4*)(gAf + k0 + 8);
      float4 f3 = *(const float4*)(gAf + k0 + 12);
      a0[0] = (bf16_t)f0.x; a0[1] = (bf16_t)f0.y; a0[2] = (bf16_t)f0.z; a0[3] = (bf16_t)f0.w;
      a0[4] = (bf16_t)f1.x; a0[5] = (bf16_t)f1.y; a0[6] = (bf16_t)f1.z; a0[7] = (bf16_t)f1.w;
      a1[0] = (bf16_t)f2.x; a1[1] = (bf16_t)f2.y; a1[2] = (bf16_t)f2.z; a1[3] = (bf16_t)f2.w;
      a1[4] = (bf16_t)f3.x; a1[5] = (bf16_t)f3.y; a1[6] = (bf16_t)f3.z; a1[7] = (bf16_t)f3.w;
    }
    {
      const float s = gS[k0 >> 5];
      int qv[16];
      *(int4*)&qv[0] = *(const int4*)(gQ + k0);
      *(int4*)&qv[4] = *(const int4*)(gQ + k0 + 4);
      *(int4*)&qv[8] = *(const int4*)(gQ + k0 + 8);
      *(int4*)&qv[12] = *(const int4*)(gQ + k0 + 12);
#pragma unroll
      for (int j = 0; j < 8; ++j) b0[j] = (bf16_t)((float)(qv[j] - QOFF) * s);
#pragma unroll
      for (int j = 0; j < 8; ++j)
        b1[j] = (bf16_t)((float)(qv[8 + j] - QOFF) * s);
    }

    __syncthreads();
    *(bf16x8*)&lsA[e] = a0;
    *(bf16x8*)&lsA[e + 8] = a1;
    *(bf16x8*)&lsB[e] = b0;
    *(bf16x8*)&lsB[e + 8] = b1;
    __syncthreads();

    bf16x8 af[4], bfv[4];
#pragma unroll
    for (int i = 0; i < 4; ++i) {
      af[i] = *(const bf16x8*)&lsA[(wm + i * 16 + r) * 32 + qd * 8];
      bfv[i] = *(const bf16x8*)&lsB[(wn + i * 16 + r) * 32 + qd * 8];
    }
#pragma unroll
    for (int mi = 0; mi < 4; ++mi)
#pragma unroll
      for (int ni = 0; ni < 4; ++ni)
        acc[mi][ni] = __builtin_amdgcn_mfma_f32_16x16x32_bf16(
            af[mi], bfv[ni], acc[mi][ni], 0, 0, 0);
  }

#pragma unroll
  for (int ni = 0; ni < 4; ++ni) {
    const int n = n0 + wn + ni * 16 + r;
    const float bv = bias[n];
#pragma unroll
    for (int mi = 0; mi < 4; ++mi) {
      const int mbase = m0 + wm + mi * 16 + qd * 4;
#pragma unroll
      for (int reg = 0; reg < 4; ++reg) {
        C[(size_t)(mbase + reg) * N + n] = acc[mi][ni][reg] + bv;
      }
    }
  }
}

// ---------------------------------------------------------------------------
extern "C" void kernel_launch(void* const* d_in, const int* in_sizes, int n_in,
                              void* d_out, int out_size, void* d_ws,
                              size_t ws_size, hipStream_t stream) {
  const float* x = (const float*)d_in[0];       // [M, K] fp32 (f16 upcast)
  const int* qw = (const int*)d_in[1];          // [O, K] int32
  const float* scales = (const float*)d_in[2];  // [O, NB] fp32
  const float* bias = (const float*)d_in[3];    // [O] fp32
  float* out = (float*)d_out;                   // [M, O] fp32

  const int O = in_sizes[3];       // 4096
  const int K = in_sizes[1] / O;   // 4096
  const int NB = in_sizes[2] / O;  // 128
  const int M = in_sizes[0] / K;   // 4096
  (void)n_in; (void)out_size;

  const size_t Wbytes = (size_t)O * K * sizeof(bf16_t);  // 32 MiB
  const size_t Xbytes = (size_t)M * K * sizeof(bf16_t);  // 32 MiB

  if (ws_size >= Wbytes + Xbytes) {
    bf16_t* W = (bf16_t*)d_ws;
    bf16_t* Xb = (bf16_t*)((char*)d_ws + Wbytes);
    const int nDeq = (int)((size_t)O * K / 2048);
    const int nCvt = (int)((size_t)M * K / 2048);
    prep_kernel<<<nDeq + nCvt, 256, 0, stream>>>(qw, scales, x, W, Xb, K, NB,
                                                 nDeq);
    if ((M % 256) == 0 && (O % 256) == 0 && (K % 128) == 0) {
      const int nwg = (M / 256) * (O / 256);
      gemm_8ph<<<nwg, 512, 0, stream>>>(Xb, W, bias, out, M, O, K);
    } else {
      dim3 grid(O / 128, M / 128);
      gemm_db<<<grid, 256, 0, stream>>>(Xb, W, bias, out, M, O, K);
    }
  } else {
    dim3 grid(O / 128, M / 128);
    gemm_fused<<<grid, 256, 0, stream>>>(x, qw, scales, bias, out, M, O, K,
                                         NB);
  }
}

// Round 2
// 292.490 us; speedup vs baseline: 1.0407x; 1.0206x over previous
//
#include <hip/hip_runtime.h>
#include <stdint.h>

// Q8_0-style dequant + linear. Harness upcasts f16 -> fp32: x/scales/bias are
// const float*, out is float*. q_weight is int32.
//   W[o,k] = (q[o,k]-128) * scales[o,k/32]
//   out[m,o] = sum_k x[m,k]*W[o,k] + bias[o]   (bf16 MFMA, fp32 accum/out)
// M = 4096, N = O = 4096, K = 4096.
//
// R9: same 256x256 8-phase tiling as R8 (swizzle verified: bank conflicts
// 1.26e7 -> 0), but fix the phase serialization R8's counters exposed
// (MfmaUtil stuck at 40%, per-iter time = LDS-drain + MFMA *summed*):
//  - REMOVE the explicit s_waitcnt lgkmcnt(0) full drains. The compiler
//    emits per-MFMA counted lgkmcnt waits, so each wave starts MFMA #1 as
//    soon as its first operands land and the LDS drain tail overlaps the
//    MFMA cluster (m97 asm evidence: compiler lgkm scheduling is
//    near-optimal; my drain was defeating it).
//  - ONE barrier per phase (8/iter, was 16). Safety: every ds_read issued in
//    phase p is consumed by an MFMA in phase p (fine-grained wait) => all of
//    a wave's reads complete before it reaches barrier(p) => stage writes
//    into that region issued in phase p+1 (post-barrier) cannot race. The
//    vmcnt(4)+barrier landed-certification points are unchanged.
//  - Counted vmcnt(4) only at P4/P8 (never 0 in-loop), setprio around MFMA,
//    T1 XCD swizzle, T2 both-sides XOR swizzle: all retained from R8.

#define QOFF 128

typedef __bf16 bf16_t;
typedef __bf16 bf16x8 __attribute__((ext_vector_type(8)));
typedef float f32x4 __attribute__((ext_vector_type(4)));

// s_waitcnt simm16: [3:0] vmcnt lo, [6:4] expcnt(7=none), [11:8] lgkmcnt,
// [15:14] vmcnt hi.
#define W_VM4 0x0F74    // vmcnt(4) only (lgkm=15)
#define W_VM0 0x0F70    // vmcnt(0) only

// ---------------------------------------------------------------------------
// Prep: blocks [0, nDeq) dequant q->W (bf16); rest convert x fp32->bf16.
// ---------------------------------------------------------------------------
__global__ __launch_bounds__(256) void prep_kernel(
    const int* __restrict__ q, const float* __restrict__ scales,
    const float* __restrict__ X, bf16_t* __restrict__ W,
    bf16_t* __restrict__ Xb, int K, int NB, int nDeq) {
  const int b = blockIdx.x;
  if (b < nDeq) {
    const size_t e = ((size_t)b * 256 + threadIdx.x) * 8;
    const int o = (int)(e / (size_t)K);
    const int i = (int)(e % (size_t)K);
    const float s = scales[o * NB + (i >> 5)];
    int4 a = *(const int4*)(q + e);
    int4 c = *(const int4*)(q + e + 4);
    const int* av = (const int*)&a;
    const int* cv = (const int*)&c;
    bf16x8 t;
#pragma unroll
    for (int j = 0; j < 4; ++j) t[j] = (bf16_t)((float)(av[j] - QOFF) * s);
#pragma unroll
    for (int j = 0; j < 4; ++j) t[4 + j] = (bf16_t)((float)(cv[j] - QOFF) * s);
    *(bf16x8*)(W + e) = t;
  } else {
    const size_t e = ((size_t)(b - nDeq) * 256 + threadIdx.x) * 8;
    float4 a = *(const float4*)(X + e);
    float4 c = *(const float4*)(X + e + 4);
    bf16x8 t;
    t[0] = (bf16_t)a.x; t[1] = (bf16_t)a.y; t[2] = (bf16_t)a.z; t[3] = (bf16_t)a.w;
    t[4] = (bf16_t)c.x; t[5] = (bf16_t)c.y; t[6] = (bf16_t)c.z; t[7] = (bf16_t)c.w;
    *(bf16x8*)(Xb + e) = t;
  }
}

// ---------------------------------------------------------------------------
__device__ __forceinline__ void async16(bf16_t* lds, const bf16_t* g) {
  __builtin_amdgcn_global_load_lds(
      (const __attribute__((address_space(1))) unsigned int*)(const void*)g,
      (__attribute__((address_space(3))) unsigned int*)(void*)lds, 16, 0, 0);
}

// 16 MFMA: one C-quadrant (4 frag-rows x 2 frag-cols) x K=64 (2 k-subtiles).
// QM/QN compile-time so acc indexing stays in registers (rule #20).
template <int QM, int QN>
__device__ __forceinline__ void mm_block(f32x4 (&acc)[8][4],
                                         const bf16x8 (&af)[4][2],
                                         const bf16x8 (&bv)[2][2]) {
  __builtin_amdgcn_s_setprio(1);
#pragma unroll
  for (int ks = 0; ks < 2; ++ks)
#pragma unroll
    for (int fi = 0; fi < 4; ++fi)
#pragma unroll
      for (int fj = 0; fj < 2; ++fj)
        acc[QM * 4 + fi][QN * 2 + fj] = __builtin_amdgcn_mfma_f32_16x16x32_bf16(
            af[fi][ks], bv[fj][ks], acc[QM * 4 + fi][QN * 2 + fj], 0, 0, 0);
  __builtin_amdgcn_s_setprio(0);
}

// 8 ds_read_b128: A quadrant-row (4 frag-rows x 2 k-subtiles).
__device__ __forceinline__ void rd_a(const bf16_t* base, const int* swz,
                                     bf16x8 (&af)[4][2]) {
#pragma unroll
  for (int ks = 0; ks < 2; ++ks)
#pragma unroll
    for (int fi = 0; fi < 4; ++fi)
      af[fi][ks] = *(const bf16x8*)(base + fi * 1024 + swz[ks]);
}

// 4 ds_read_b128: B quadrant (2 frag-cols x 2 k-subtiles).
__device__ __forceinline__ void rd_b(const bf16_t* base, const int* swz,
                                     bf16x8 (&bv)[2][2]) {
#pragma unroll
  for (int ks = 0; ks < 2; ++ks)
#pragma unroll
    for (int fj = 0; fj < 2; ++fj)
      bv[fj][ks] = *(const bf16x8*)(base + fj * 1024 + swz[ks]);
}

// 12 ds_reads interleaved so the first MFMAs' operands land first.
__device__ __forceinline__ void rd12(const bf16_t* abase, const bf16_t* bbase,
                                     const int* swz, bf16x8 (&af)[4][2],
                                     bf16x8 (&bv)[2][2]) {
#pragma unroll
  for (int ks = 0; ks < 2; ++ks) {
    af[0][ks] = *(const bf16x8*)(abase + swz[ks]);
    bv[0][ks] = *(const bf16x8*)(bbase + swz[ks]);
    af[1][ks] = *(const bf16x8*)(abase + 1024 + swz[ks]);
    bv[1][ks] = *(const bf16x8*)(bbase + 1024 + swz[ks]);
    af[2][ks] = *(const bf16x8*)(abase + 2048 + swz[ks]);
    af[3][ks] = *(const bf16x8*)(abase + 3072 + swz[ks]);
  }
}

// ---------------------------------------------------------------------------
// 8-phase 256x256 GEMM. Requires M%256==0, N%256==0, K%128==0.
// LDS tile layout (per operand, per buffer): 256 rows x 64 cols bf16, 128-B
// rows of 8 16-B slots; element (row, slot s) stored at slot s^(row&7).
// global_load_lds writes linearly, so the staging global address is
// pre-swizzled with the same XOR (involution, both-sides rule).
//
// Phase = { ds_reads ; stage 1 half-tile ; MFMA (compiler counted-lgkm) ;
//           [vmcnt(4)] ; s_barrier }  -- one barrier per phase.
// Safety proofs:
//  (i) stage(p+1) vs reads(p) of the same region: every read(p) feeds an
//      MFMA(p); the compiler's lgkm wait precedes that MFMA's issue, so all
//      reads complete before the wave passes barrier(p); stage issues after.
//  (ii) reads of freshly staged data: gated by vmcnt(4)+barrier at P4 (tile
//      2j+1 A+B certified) and P8 (tile t2 A+B certified) -- unchanged
//      from R8's accounting (queue at end-P4/P8 = 12 loads, first 8 = the
//      needed tile, vmcnt(4) retires exactly those).
// ---------------------------------------------------------------------------
__global__ __launch_bounds__(512, 2) void gemm_8ph(
    const bf16_t* __restrict__ A,   // [M, K] x (bf16)
    const bf16_t* __restrict__ B,   // [N, K] dequantized W (bf16)
    const float* __restrict__ bias, // [N]
    float* __restrict__ C,          // [M, N] fp32
    int M, int N, int K) {
  __shared__ bf16_t lsA[2][256 * 64];  // 32 KiB / buf
  __shared__ bf16_t lsB[2][256 * 64];  // 32 KiB / buf

  const int tid = threadIdx.x;
  const int lane = tid & 63;
  const int wave = tid >> 6;
  const int r = lane & 15;   // frag row (A) / col (B)
  const int qd = lane >> 4;  // k-slot within subtile (in), row-group (C/D)
  const int wm = (wave >> 2) * 128;  // wave-tile m origin
  const int wn = (wave & 3) * 64;    // wave-tile n origin

  // T1: bijective XCD swizzle (nwg % 8 == 0 guaranteed by launcher shapes).
  const int nbx = N >> 8;
  const int nwg = gridDim.x;
  int wg = blockIdx.x;
  if ((nwg & 7) == 0) wg = (wg & 7) * (nwg >> 3) + (wg >> 3);
  const int m0 = (wg / nbx) * 256;
  const int n0 = (wg % nbx) * 256;

  f32x4 acc[8][4] = {};

  // Staging: half-tile = 128 rows x 64 cols = 16 KiB = 2 issues of 512x16B.
  // Thread t covers (row = t/8, slot = t%8) of a 64-row part; source slot is
  // pre-swizzled: s' = (t%8) ^ (row&7).
  const int srow = tid >> 3;                     // 0..63
  const int sslot = (tid & 7) ^ (srow & 7);      // pre-swizzled k-slot
  const bf16_t* gA0 = A + (size_t)(m0 + srow) * K + sslot * 8;
  const bf16_t* gB0 = B + (size_t)(n0 + srow) * K + sslot * 8;

  auto stgA = [&](bf16_t* dstTile, int half, int koff) {
    bf16_t* d = dstTile + half * 8192 + tid * 8;
    const bf16_t* g = gA0 + (size_t)(half * 128) * K + koff;
    async16(d, g);
    async16(d + 4096, g + 64 * (size_t)K);
  };
  auto stgB = [&](bf16_t* dstTile, int half, int koff) {
    bf16_t* d = dstTile + half * 8192 + tid * 8;
    const bf16_t* g = gB0 + (size_t)(half * 128) * K + koff;
    async16(d, g);
    async16(d + 4096, g + 64 * (size_t)K);
  };

  // Per-lane read offsets: elem = row*64 + ((ks*4+qd)^(row&7))*8, row&7==r&7.
  const int swz[2] = {(qd ^ (r & 7)) * 8, ((4 + qd) ^ (r & 7)) * 8};
  const bf16_t* a0base = &lsA[0][(wm + r) * 64];
  const bf16_t* a1base = &lsA[1][(wm + r) * 64];
  const bf16_t* b0base = &lsB[0][(wn + r) * 64];
  const bf16_t* b1base = &lsB[1][(wn + r) * 64];

  const int NT = K >> 6;      // K-tiles (even)
  const int NITER = NT >> 1;  // iterations (2 tiles each)

  // Prologue: tile 0 (buf0, 8 loads) + B of tile 1 (buf1, 4 loads);
  // vmcnt(4) leaves B(1) in flight == steady-state loop entry invariant.
  stgA(lsA[0], 0, 0);
  stgA(lsA[0], 1, 0);
  stgB(lsB[0], 0, 0);
  stgB(lsB[0], 1, 0);
  stgB(lsB[1], 0, 64);
  stgB(lsB[1], 1, 64);
  __builtin_amdgcn_s_waitcnt(W_VM4);
  __builtin_amdgcn_s_barrier();

  bf16x8 af[4][2], bf0[2][2], bf1[2][2];

#pragma unroll 1
  for (int j = 0; j < NITER; ++j) {
    // Stage targets: A(2j+1)->buf1 @P1,P2; B(t2)->buf0 @P3,P4;
    // A(t2)->buf0 @P5,P6; B(t3)->buf1 @P7,P8. Wrapped tiles (last iter) stage
    // valid-but-unread data; parity preserved (NT even).
    const int k1 = (2 * j + 1) * 64;
    int t2 = 2 * j + 2; if (t2 >= NT) t2 -= NT;
    int t3 = 2 * j + 3; if (t3 >= NT) t3 -= NT;
    const int k2 = t2 * 64;
    const int k3 = t3 * 64;

    // ---- P1: tile 2j (buf0), quadrant (0,0). 12 ds_reads.
    rd12(a0base, b0base, swz, af, bf0);
    stgA(lsA[1], 0, k1);
    mm_block<0, 0>(acc, af, bf0);
    __builtin_amdgcn_s_barrier();
    // ---- P2: (0,1). 4 ds_reads.
    rd_b(b0base + 2048, swz, bf1);
    stgA(lsA[1], 1, k1);
    mm_block<0, 1>(acc, af, bf1);
    __builtin_amdgcn_s_barrier();
    // ---- P3: (1,1). 8 ds_reads. buf0.B reads done by barrier(P2) ->
    // stage B(t2) here is safe.
    rd_a(a0base + 4096, swz, af);
    stgB(lsB[0], 0, k2);
    mm_block<1, 1>(acc, af, bf1);
    __builtin_amdgcn_s_barrier();
    // ---- P4: (1,0) reusing bf0. vmcnt(4): tile 2j+1 (A @P1,P2 + B @P7,P8
    // prev iter) fully landed; B(t2) stays in flight across the barrier.
    stgB(lsB[0], 1, k2);
    mm_block<1, 0>(acc, af, bf0);
    __builtin_amdgcn_s_waitcnt(W_VM4);
    __builtin_amdgcn_s_barrier();

    // ---- P5: tile 2j+1 (buf1), (0,0). buf0.A reads done by barrier(P3) ->
    // stage A(t2).
    rd12(a1base, b1base, swz, af, bf0);
    stgA(lsA[0], 0, k2);
    mm_block<0, 0>(acc, af, bf0);
    __builtin_amdgcn_s_barrier();
    // ---- P6: (0,1).
    rd_b(b1base + 2048, swz, bf1);
    stgA(lsA[0], 1, k2);
    mm_block<0, 1>(acc, af, bf1);
    __builtin_amdgcn_s_barrier();
    // ---- P7: (1,1). buf1.B reads done by barrier(P6) -> stage B(t3).
    rd_a(a1base + 4096, swz, af);
    stgB(lsB[1], 0, k3);
    mm_block<1, 1>(acc, af, bf1);
    __builtin_amdgcn_s_barrier();
    // ---- P8: (1,0). vmcnt(4): tile t2 (B @P3,P4 + A @P5,P6) fully landed
    // for next-iter P1; B(t3) stays in flight.
    stgB(lsB[1], 1, k3);
    mm_block<1, 0>(acc, af, bf0);
    __builtin_amdgcn_s_waitcnt(W_VM4);
    __builtin_amdgcn_s_barrier();
  }

  // Drain wrapped in-flight DMAs before exit (LDS reuse safety).
  __builtin_amdgcn_s_waitcnt(W_VM0);

  // Epilogue: C/D mapping col = lane&15 (n), row = qd*4 + reg (m). fp32 out.
#pragma unroll
  for (int ni = 0; ni < 4; ++ni) {
    const int n = n0 + wn + ni * 16 + r;
    const float bv = bias[n];
#pragma unroll
    for (int mi = 0; mi < 8; ++mi) {
      const int mbase = m0 + wm + mi * 16 + qd * 4;
#pragma unroll
      for (int reg = 0; reg < 4; ++reg) {
        C[(size_t)(mbase + reg) * N + n] = acc[mi][ni][reg] + bv;
      }
    }
  }
}

// ---------------------------------------------------------------------------
// Fallback GEMM (any K%32==0): 128x128 double-buffered version.
// ---------------------------------------------------------------------------
__global__ __launch_bounds__(256) void gemm_db(
    const bf16_t* __restrict__ A, const bf16_t* __restrict__ B,
    const float* __restrict__ bias, float* __restrict__ C, int M, int N,
    int K) {
  __shared__ bf16_t lsA[2][128 * 32];
  __shared__ bf16_t lsB[2][128 * 32];

  const int tid = threadIdx.x;
  const int lane = tid & 63;
  const int wave = tid >> 6;
  const int m0 = blockIdx.y * 128;
  const int n0 = blockIdx.x * 128;
  const int wm = (wave >> 1) * 64;
  const int wn = (wave & 1) * 64;
  const int r = lane & 15;
  const int qd = lane >> 4;

  f32x4 acc[4][4] = {};

  const int e0 = tid * 8;
  const int e1 = 2048 + tid * 8;
  const bf16_t* gA0 = A + (size_t)(m0 + (e0 >> 5)) * K + (e0 & 31);
  const bf16_t* gA1 = A + (size_t)(m0 + (e1 >> 5)) * K + (e1 & 31);
  const bf16_t* gB0 = B + (size_t)(n0 + (e0 >> 5)) * K + (e0 & 31);
  const bf16_t* gB1 = B + (size_t)(n0 + (e1 >> 5)) * K + (e1 & 31);

  async16(&lsA[0][e0], gA0);
  async16(&lsA[0][e1], gA1);
  async16(&lsB[0][e0], gB0);
  async16(&lsB[0][e1], gB1);

  int buf = 0;
  for (int k0 = 0; k0 < K; k0 += 32, buf ^= 1) {
    __syncthreads();
    if (k0 + 32 < K) {
      const int nk = k0 + 32;
      async16(&lsA[buf ^ 1][e0], gA0 + nk);
      async16(&lsA[buf ^ 1][e1], gA1 + nk);
      async16(&lsB[buf ^ 1][e0], gB0 + nk);
      async16(&lsB[buf ^ 1][e1], gB1 + nk);
    }
    bf16x8 af[4], bfv[4];
#pragma unroll
    for (int i = 0; i < 4; ++i) {
      af[i] = *(const bf16x8*)&lsA[buf][(wm + i * 16 + r) * 32 + qd * 8];
      bfv[i] = *(const bf16x8*)&lsB[buf][(wn + i * 16 + r) * 32 + qd * 8];
    }
#pragma unroll
    for (int mi = 0; mi < 4; ++mi)
#pragma unroll
      for (int ni = 0; ni < 4; ++ni)
        acc[mi][ni] = __builtin_amdgcn_mfma_f32_16x16x32_bf16(
            af[mi], bfv[ni], acc[mi][ni], 0, 0, 0);
  }

#pragma unroll
  for (int ni = 0; ni < 4; ++ni) {
    const int n = n0 + wn + ni * 16 + r;
    const float bv = bias[n];
#pragma unroll
    for (int mi = 0; mi < 4; ++mi) {
      const int mbase = m0 + wm + mi * 16 + qd * 4;
#pragma unroll
      for (int reg = 0; reg < 4; ++reg) {
        C[(size_t)(mbase + reg) * N + n] = acc[mi][ni][reg] + bv;
      }
    }
  }
}

// ---------------------------------------------------------------------------
// Fallback (small ws): register-staged GEMM, fused A-convert + B-dequant.
// ---------------------------------------------------------------------------
__global__ __launch_bounds__(256) void gemm_fused(
    const float* __restrict__ Af, const int* __restrict__ q,
    const float* __restrict__ scales, const float* __restrict__ bias,
    float* __restrict__ C, int M, int N, int K, int NB) {
  __shared__ bf16_t lsA[128 * 32];
  __shared__ bf16_t lsB[128 * 32];

  const int tid = threadIdx.x;
  const int lane = tid & 63;
  const int wave = tid >> 6;
  const int m0 = blockIdx.y * 128;
  const int n0 = blockIdx.x * 128;
  const int wm = (wave >> 1) * 64;
  const int wn = (wave & 1) * 64;
  const int r = lane & 15;
  const int qd = lane >> 4;

  const int e = tid * 16;
  const int row = e >> 5;
  const int col = e & 31;

  const float* gAf = Af + (size_t)(m0 + row) * K + col;
  const int* gQ = q + (size_t)(n0 + row) * K + col;
  const float* gS = scales + (size_t)(n0 + row) * NB;

  f32x4 acc[4][4] = {};

  for (int k0 = 0; k0 < K; k0 += 32) {
    bf16x8 a0, a1, b0, b1;
    {
      float4 f0 = *(const float4*)(gAf + k0);
      float4 f1 = *(const float4*)(gAf + k0 + 4);
      float4 f2 = *(const float4*)(gAf + k0 + 8);
      float4 f3 = *(const float4*)(gAf + k0 + 12);
      a0[0] = (bf16_t)f0.x; a0[1] = (bf16_t)f0.y; a0[2] = (bf16_t)f0.z; a0[3] = (bf16_t)f0.w;
      a0[4] = (bf16_t)f1.x; a0[5] = (bf16_t)f1.y; a0[6] = (bf16_t)f1.z; a0[7] = (bf16_t)f1.w;
      a1[0] = (bf16_t)f2.x; a1[1] = (bf16_t)f2.y; a1[2] = (bf16_t)f2.z; a1[3] = (bf16_t)f2.w;
      a1[4] = (bf16_t)f3.x; a1[5] = (bf16_t)f3.y; a1[6] = (bf16_t)f3.z; a1[7] = (bf16_t)f3.w;
    }
    {
      const float s = gS[k0 >> 5];
      int qv[16];
      *(int4*)&qv[0] = *(const int4*)(gQ + k0);
      *(int4*)&qv[4] = *(const int4*)(gQ + k0 + 4);
      *(int4*)&qv[8] = *(const int4*)(gQ + k0 + 8);
      *(int4*)&qv[12] = *(const int4*)(gQ + k0 + 12);
#pragma unroll
      for (int j = 0; j < 8; ++j) b0[j] = (bf16_t)((float)(qv[j] - QOFF) * s);
#pragma unroll
      for (int j = 0; j < 8; ++j)
        b1[j] = (bf16_t)((float)(qv[8 + j] - QOFF) * s);
    }

    __syncthreads();
    *(bf16x8*)&lsA[e] = a0;
    *(bf16x8*)&lsA[e + 8] = a1;
    *(bf16x8*)&lsB[e] = b0;
    *(bf16x8*)&lsB[e + 8] = b1;
    __syncthreads();

    bf16x8 af[4], bfv[4];
#pragma unroll
    for (int i = 0; i < 4; ++i) {
      af[i] = *(const bf16x8*)&lsA[(wm + i * 16 + r) * 32 + qd * 8];
      bfv[i] = *(const bf16x8*)&lsB[(wn + i * 16 + r) * 32 + qd * 8];
    }
#pragma unroll
    for (int mi = 0; mi < 4; ++mi)
#pragma unroll
      for (int ni = 0; ni < 4; ++ni)
        acc[mi][ni] = __builtin_amdgcn_mfma_f32_16x16x32_bf16(
            af[mi], bfv[ni], acc[mi][ni], 0, 0, 0);
  }

#pragma unroll
  for (int ni = 0; ni < 4; ++ni) {
    const int n = n0 + wn + ni * 16 + r;
    const float bv = bias[n];
#pragma unroll
    for (int mi = 0; mi < 4; ++mi) {
      const int mbase = m0 + wm + mi * 16 + qd * 4;
#pragma unroll
      for (int reg = 0; reg < 4; ++reg) {
        C[(size_t)(mbase + reg) * N + n] = acc[mi][ni][reg] + bv;
      }
    }
  }
}

// ---------------------------------------------------------------------------
extern "C" void kernel_launch(void* const* d_in, const int* in_sizes, int n_in,
                              void* d_out, int out_size, void* d_ws,
                              size_t ws_size, hipStream_t stream) {
  const float* x = (const float*)d_in[0];       // [M, K] fp32 (f16 upcast)
  const int* qw = (const int*)d_in[1];          // [O, K] int32
  const float* scales = (const float*)d_in[2];  // [O, NB] fp32
  const float* bias = (const float*)d_in[3];    // [O] fp32
  float* out = (float*)d_out;                   // [M, O] fp32

  const int O = in_sizes[3];       // 4096
  const int K = in_sizes[1] / O;   // 4096
  const int NB = in_sizes[2] / O;  // 128
  const int M = in_sizes[0] / K;   // 4096
  (void)n_in; (void)out_size;

  const size_t Wbytes = (size_t)O * K * sizeof(bf16_t);  // 32 MiB
  const size_t Xbytes = (size_t)M * K * sizeof(bf16_t);  // 32 MiB

  if (ws_size >= Wbytes + Xbytes) {
    bf16_t* W = (bf16_t*)d_ws;
    bf16_t* Xb = (bf16_t*)((char*)d_ws + Wbytes);
    const int nDeq = (int)((size_t)O * K / 2048);
    const int nCvt = (int)((size_t)M * K / 2048);
    prep_kernel<<<nDeq + nCvt, 256, 0, stream>>>(qw, scales, x, W, Xb, K, NB,
                                                 nDeq);
    if ((M % 256) == 0 && (O % 256) == 0 && (K % 128) == 0) {
      const int nwg = (M / 256) * (O / 256);
      gemm_8ph<<<nwg, 512, 0, stream>>>(Xb, W, bias, out, M, O, K);
    } else {
      dim3 grid(O / 128, M / 128);
      gemm_db<<<grid, 256, 0, stream>>>(Xb, W, bias, out, M, O, K);
    }
  } else {
    dim3 grid(O / 128, M / 128);
    gemm_fused<<<grid, 256, 0, stream>>>(x, qw, scales, bias, out, M, O, K,
                                         NB);
  }
}

// Round 3
// 287.263 us; speedup vs baseline: 1.0597x; 1.0182x over previous
//
#include <hip/hip_runtime.h>
#include <stdint.h>

// Q8_0-style dequant + linear. Harness upcasts f16 -> fp32: x/scales/bias are
// const float*, out is float*. q_weight is int32.
//   W[o,k] = (q[o,k]-128) * scales[o,k/32]
//   out[m,o] = sum_k x[m,k]*W[o,k] + bias[o]   (bf16 MFMA, fp32 accum/out)
// M = 4096, N = O = 4096, K = 4096.
//
// R10: fragment-level software pipeline (distance 1 segment). R9's counters
// showed per-iter time = LDS + MFMA summed (MfmaUtil 43%): reads and their
// consuming MFMAs shared an inter-barrier segment, so barriers serialized
// LDS drain against MFMA. Now segment k issues the reads for segment k+1's
// MFMA. Quadrant order (0,0)->(1,0)->(0,1)->(1,1) per K-tile makes every
// segment's read targets disjoint from its MFMA's operand sets (no WAR), so
// reads co-issue with MFMAs and drain under them. Costs one extra A-frag
// set (+32 VGPR). vmcnt(4) once per tile (counted, never 0). Swizzle (bank
// conflicts = 0), XCD swizzle, setprio retained.

#define QOFF 128

typedef __bf16 bf16_t;
typedef __bf16 bf16x8 __attribute__((ext_vector_type(8)));
typedef float f32x4 __attribute__((ext_vector_type(4)));

// s_waitcnt simm16: [3:0] vmcnt lo, [6:4] expcnt(7=none), [11:8] lgkmcnt,
// [15:14] vmcnt hi.
#define W_VM4 0x0F74    // vmcnt(4) only (lgkm=15)
#define W_VM0 0x0F70    // vmcnt(0) only

// ---------------------------------------------------------------------------
// Prep: blocks [0, nDeq) dequant q->W (bf16); rest convert x fp32->bf16.
// ---------------------------------------------------------------------------
__global__ __launch_bounds__(256) void prep_kernel(
    const int* __restrict__ q, const float* __restrict__ scales,
    const float* __restrict__ X, bf16_t* __restrict__ W,
    bf16_t* __restrict__ Xb, int K, int NB, int nDeq) {
  const int b = blockIdx.x;
  if (b < nDeq) {
    const size_t e = ((size_t)b * 256 + threadIdx.x) * 8;
    const int o = (int)(e / (size_t)K);
    const int i = (int)(e % (size_t)K);
    const float s = scales[o * NB + (i >> 5)];
    int4 a = *(const int4*)(q + e);
    int4 c = *(const int4*)(q + e + 4);
    const int* av = (const int*)&a;
    const int* cv = (const int*)&c;
    bf16x8 t;
#pragma unroll
    for (int j = 0; j < 4; ++j) t[j] = (bf16_t)((float)(av[j] - QOFF) * s);
#pragma unroll
    for (int j = 0; j < 4; ++j) t[4 + j] = (bf16_t)((float)(cv[j] - QOFF) * s);
    *(bf16x8*)(W + e) = t;
  } else {
    const size_t e = ((size_t)(b - nDeq) * 256 + threadIdx.x) * 8;
    float4 a = *(const float4*)(X + e);
    float4 c = *(const float4*)(X + e + 4);
    bf16x8 t;
    t[0] = (bf16_t)a.x; t[1] = (bf16_t)a.y; t[2] = (bf16_t)a.z; t[3] = (bf16_t)a.w;
    t[4] = (bf16_t)c.x; t[5] = (bf16_t)c.y; t[6] = (bf16_t)c.z; t[7] = (bf16_t)c.w;
    *(bf16x8*)(Xb + e) = t;
  }
}

// ---------------------------------------------------------------------------
__device__ __forceinline__ void async16(bf16_t* lds, const bf16_t* g) {
  __builtin_amdgcn_global_load_lds(
      (const __attribute__((address_space(1))) unsigned int*)(const void*)g,
      (__attribute__((address_space(3))) unsigned int*)(void*)lds, 16, 0, 0);
}

// 16 MFMA: one C-quadrant (4 frag-rows x 2 frag-cols) x K=64 (2 k-subtiles).
// QM/QN compile-time so acc indexing stays in registers (rule #20).
template <int QM, int QN>
__device__ __forceinline__ void mm_block(f32x4 (&acc)[8][4],
                                         const bf16x8 (&af)[4][2],
                                         const bf16x8 (&bv)[2][2]) {
  __builtin_amdgcn_s_setprio(1);
#pragma unroll
  for (int ks = 0; ks < 2; ++ks)
#pragma unroll
    for (int fi = 0; fi < 4; ++fi)
#pragma unroll
      for (int fj = 0; fj < 2; ++fj)
        acc[QM * 4 + fi][QN * 2 + fj] = __builtin_amdgcn_mfma_f32_16x16x32_bf16(
            af[fi][ks], bv[fj][ks], acc[QM * 4 + fi][QN * 2 + fj], 0, 0, 0);
  __builtin_amdgcn_s_setprio(0);
}

// 8 ds_read_b128: A quadrant-row (4 frag-rows x 2 k-subtiles).
__device__ __forceinline__ void rd_a(const bf16_t* base, const int* swz,
                                     bf16x8 (&af)[4][2]) {
#pragma unroll
  for (int ks = 0; ks < 2; ++ks)
#pragma unroll
    for (int fi = 0; fi < 4; ++fi)
      af[fi][ks] = *(const bf16x8*)(base + fi * 1024 + swz[ks]);
}

// 4 ds_read_b128: B quadrant (2 frag-cols x 2 k-subtiles).
__device__ __forceinline__ void rd_b(const bf16_t* base, const int* swz,
                                     bf16x8 (&bv)[2][2]) {
#pragma unroll
  for (int ks = 0; ks < 2; ++ks)
#pragma unroll
    for (int fj = 0; fj < 2; ++fj)
      bv[fj][ks] = *(const bf16x8*)(base + fj * 1024 + swz[ks]);
}

// 12 ds_reads interleaved so the earliest-consumed operands land first.
__device__ __forceinline__ void rd12(const bf16_t* abase, const bf16_t* bbase,
                                     const int* swz, bf16x8 (&af)[4][2],
                                     bf16x8 (&bv)[2][2]) {
#pragma unroll
  for (int ks = 0; ks < 2; ++ks) {
    af[0][ks] = *(const bf16x8*)(abase + swz[ks]);
    bv[0][ks] = *(const bf16x8*)(bbase + swz[ks]);
    af[1][ks] = *(const bf16x8*)(abase + 1024 + swz[ks]);
    bv[1][ks] = *(const bf16x8*)(bbase + 1024 + swz[ks]);
    af[2][ks] = *(const bf16x8*)(abase + 2048 + swz[ks]);
    af[3][ks] = *(const bf16x8*)(abase + 3072 + swz[ks]);
  }
}

// ---------------------------------------------------------------------------
// Pipelined 256x256 GEMM. Requires M%256==0, N%256==0, K%128==0.
// LDS tile layout (per operand, per buffer): 256 rows x 64 cols bf16, 128-B
// rows of 8 16-B slots; element (row, slot s) stored at slot s^(row&7).
// global_load_lds writes linearly, so the staging global address is
// pre-swizzled with the same XOR (involution, both-sides rule).
//
// Per K-tile t (buf b = t&1), 4 segments; reads in segment k feed the MFMA
// of segment k+1 (registers disjoint from segment k's MFMA operands):
//  G1: MFMA(0,0){af_lo,bv0}; read af_hi(b);            barrier
//  G2: MFMA(1,0){af_hi,bv0}; read bv1(b);              barrier
//  G3: MFMA(0,1){af_lo,bv1}; stage A(t+2)->b [4 DMA];  vmcnt(4); barrier
//  G4: MFMA(1,1){af_hi,bv1}; read af_lo+bv0(b^1);
//      stage B(t+2)->b [4 DMA];                        barrier
// Region freedom: af_lo(b)/bv0(b) reads (prev G4) complete before G1's MFMA
// (counted lgkm) => free after barrier(G1); af_hi after barrier(G2); bv1
// after barrier(G3). So stage A in G3 (A free after G2) and B in G4 (B free
// after G3) are race-free.
// DMA accounting (per wave): 8 in flight at tile start (A(t+1)+B(t+1));
// G3 adds 4 -> 12; vmcnt(4)+barrier retires A(t+1)+B(t+1) (certifies buf b^1
// = tile t+1 before G4 reads it); G4 adds 4 -> 8 at next tile start.
// Loads retired >=3 segments after issue -- never a stall, never 0 in-loop.
// ---------------------------------------------------------------------------
__global__ __launch_bounds__(512, 2) void gemm_8ph(
    const bf16_t* __restrict__ A,   // [M, K] x (bf16)
    const bf16_t* __restrict__ B,   // [N, K] dequantized W (bf16)
    const float* __restrict__ bias, // [N]
    float* __restrict__ C,          // [M, N] fp32
    int M, int N, int K) {
  __shared__ bf16_t lsA[2][256 * 64];  // 32 KiB / buf
  __shared__ bf16_t lsB[2][256 * 64];  // 32 KiB / buf

  const int tid = threadIdx.x;
  const int lane = tid & 63;
  const int wave = tid >> 6;
  const int r = lane & 15;   // frag row (A) / col (B)
  const int qd = lane >> 4;  // k-slot within subtile (in), row-group (C/D)
  const int wm = (wave >> 2) * 128;  // wave-tile m origin
  const int wn = (wave & 3) * 64;    // wave-tile n origin

  // T1: bijective XCD swizzle (nwg % 8 == 0 guaranteed by launcher shapes).
  const int nbx = N >> 8;
  const int nwg = gridDim.x;
  int wg = blockIdx.x;
  if ((nwg & 7) == 0) wg = (wg & 7) * (nwg >> 3) + (wg >> 3);
  const int m0 = (wg / nbx) * 256;
  const int n0 = (wg % nbx) * 256;

  f32x4 acc[8][4] = {};

  // Staging: half-tile = 128 rows x 64 cols = 16 KiB = 2 issues of 512x16B.
  // Thread t covers (row = t/8, slot = t%8) of a 64-row part; source slot is
  // pre-swizzled: s' = (t%8) ^ (row&7).
  const int srow = tid >> 3;                     // 0..63
  const int sslot = (tid & 7) ^ (srow & 7);      // pre-swizzled k-slot
  const bf16_t* gA0 = A + (size_t)(m0 + srow) * K + sslot * 8;
  const bf16_t* gB0 = B + (size_t)(n0 + srow) * K + sslot * 8;

  auto stgA = [&](bf16_t* dstTile, int half, int koff) {
    bf16_t* d = dstTile + half * 8192 + tid * 8;
    const bf16_t* g = gA0 + (size_t)(half * 128) * K + koff;
    async16(d, g);
    async16(d + 4096, g + 64 * (size_t)K);
  };
  auto stgB = [&](bf16_t* dstTile, int half, int koff) {
    bf16_t* d = dstTile + half * 8192 + tid * 8;
    const bf16_t* g = gB0 + (size_t)(half * 128) * K + koff;
    async16(d, g);
    async16(d + 4096, g + 64 * (size_t)K);
  };

  // Per-lane read offsets: elem = row*64 + ((ks*4+qd)^(row&7))*8, row&7==r&7.
  const int swz[2] = {(qd ^ (r & 7)) * 8, ((4 + qd) ^ (r & 7)) * 8};
  const bf16_t* a0base = &lsA[0][(wm + r) * 64];
  const bf16_t* a1base = &lsA[1][(wm + r) * 64];
  const bf16_t* b0base = &lsB[0][(wn + r) * 64];
  const bf16_t* b1base = &lsB[1][(wn + r) * 64];

  const int NT = K >> 6;  // K-tiles (even)

  // Fragment sets. af_lo/af_hi = A quadrant rows [wm,wm+64)/[wm+64,wm+128);
  // bv0/bv1 = B quadrant cols [wn,wn+32)/[wn+32,wn+64).
  bf16x8 af_lo[4][2], af_hi[4][2], bv0[2][2], bv1[2][2];

  // Prologue: stage A(0),B(0)->buf0, A(1)->buf1 (12 DMA); vmcnt(4)+barrier
  // certifies tile 0 (A(1) stays in flight). Then the "G4(-1)" reads of
  // tile 0, and stage B(1)->buf1 (in flight: A(1)+B(1) = 8 = invariant).
  stgA(lsA[0], 0, 0);
  stgA(lsA[0], 1, 0);
  stgB(lsB[0], 0, 0);
  stgB(lsB[0], 1, 0);
  stgA(lsA[1], 0, 64);
  stgA(lsA[1], 1, 64);
  __builtin_amdgcn_s_waitcnt(W_VM4);
  __builtin_amdgcn_s_barrier();
  rd12(a0base, b0base, swz, af_lo, bv0);
  stgB(lsB[1], 0, 64);
  stgB(lsB[1], 1, 64);

#define TILE_STEP(CUR, NXT, K2)                                       \
  /* G1 */                                                            \
  mm_block<0, 0>(acc, af_lo, bv0);                                    \
  rd_a(a##CUR##base + 4096, swz, af_hi);                              \
  __builtin_amdgcn_s_barrier();                                       \
  /* G2 */                                                            \
  mm_block<1, 0>(acc, af_hi, bv0);                                    \
  rd_b(b##CUR##base + 2048, swz, bv1);                                \
  __builtin_amdgcn_s_barrier();                                       \
  /* G3 */                                                            \
  mm_block<0, 1>(acc, af_lo, bv1);                                    \
  stgA(lsA[CUR], 0, K2);                                              \
  stgA(lsA[CUR], 1, K2);                                              \
  __builtin_amdgcn_s_waitcnt(W_VM4);                                  \
  __builtin_amdgcn_s_barrier();                                       \
  /* G4 */                                                            \
  mm_block<1, 1>(acc, af_hi, bv1);                                    \
  rd12(a##NXT##base, b##NXT##base, swz, af_lo, bv0);                  \
  stgB(lsB[CUR], 0, K2);                                              \
  stgB(lsB[CUR], 1, K2);                                              \
  __builtin_amdgcn_s_barrier();

#pragma unroll 1
  for (int j = 0; j < NT / 2; ++j) {
    // Stage tiles 2j+2 / 2j+3 (wrap mod NT on the final iterations: re-stages
    // valid-but-unread data; buf parity preserved since NT is even).
    int t2 = 2 * j + 2; if (t2 >= NT) t2 -= NT;
    int t3 = 2 * j + 3; if (t3 >= NT) t3 -= NT;
    const int k2 = t2 * 64;
    const int k3 = t3 * 64;
    TILE_STEP(0, 1, k2)  // tile 2j   in buf0
    TILE_STEP(1, 0, k3)  // tile 2j+1 in buf1
  }
#undef TILE_STEP

  // Drain wrapped in-flight DMAs before exit.
  __builtin_amdgcn_s_waitcnt(W_VM0);

  // Epilogue: C/D mapping col = lane&15 (n), row = qd*4 + reg (m). fp32 out.
#pragma unroll
  for (int ni = 0; ni < 4; ++ni) {
    const int n = n0 + wn + ni * 16 + r;
    const float bv = bias[n];
#pragma unroll
    for (int mi = 0; mi < 8; ++mi) {
      const int mbase = m0 + wm + mi * 16 + qd * 4;
#pragma unroll
      for (int reg = 0; reg < 4; ++reg) {
        C[(size_t)(mbase + reg) * N + n] = acc[mi][ni][reg] + bv;
      }
    }
  }
}

// ---------------------------------------------------------------------------
// Fallback GEMM (any K%32==0): 128x128 double-buffered version.
// ---------------------------------------------------------------------------
__global__ __launch_bounds__(256) void gemm_db(
    const bf16_t* __restrict__ A, const bf16_t* __restrict__ B,
    const float* __restrict__ bias, float* __restrict__ C, int M, int N,
    int K) {
  __shared__ bf16_t lsA[2][128 * 32];
  __shared__ bf16_t lsB[2][128 * 32];

  const int tid = threadIdx.x;
  const int lane = tid & 63;
  const int wave = tid >> 6;
  const int m0 = blockIdx.y * 128;
  const int n0 = blockIdx.x * 128;
  const int wm = (wave >> 1) * 64;
  const int wn = (wave & 1) * 64;
  const int r = lane & 15;
  const int qd = lane >> 4;

  f32x4 acc[4][4] = {};

  const int e0 = tid * 8;
  const int e1 = 2048 + tid * 8;
  const bf16_t* gA0 = A + (size_t)(m0 + (e0 >> 5)) * K + (e0 & 31);
  const bf16_t* gA1 = A + (size_t)(m0 + (e1 >> 5)) * K + (e1 & 31);
  const bf16_t* gB0 = B + (size_t)(n0 + (e0 >> 5)) * K + (e0 & 31);
  const bf16_t* gB1 = B + (size_t)(n0 + (e1 >> 5)) * K + (e1 & 31);

  async16(&lsA[0][e0], gA0);
  async16(&lsA[0][e1], gA1);
  async16(&lsB[0][e0], gB0);
  async16(&lsB[0][e1], gB1);

  int buf = 0;
  for (int k0 = 0; k0 < K; k0 += 32, buf ^= 1) {
    __syncthreads();
    if (k0 + 32 < K) {
      const int nk = k0 + 32;
      async16(&lsA[buf ^ 1][e0], gA0 + nk);
      async16(&lsA[buf ^ 1][e1], gA1 + nk);
      async16(&lsB[buf ^ 1][e0], gB0 + nk);
      async16(&lsB[buf ^ 1][e1], gB1 + nk);
    }
    bf16x8 af[4], bfv[4];
#pragma unroll
    for (int i = 0; i < 4; ++i) {
      af[i] = *(const bf16x8*)&lsA[buf][(wm + i * 16 + r) * 32 + qd * 8];
      bfv[i] = *(const bf16x8*)&lsB[buf][(wn + i * 16 + r) * 32 + qd * 8];
    }
#pragma unroll
    for (int mi = 0; mi < 4; ++mi)
#pragma unroll
      for (int ni = 0; ni < 4; ++ni)
        acc[mi][ni] = __builtin_amdgcn_mfma_f32_16x16x32_bf16(
            af[mi], bfv[ni], acc[mi][ni], 0, 0, 0);
  }

#pragma unroll
  for (int ni = 0; ni < 4; ++ni) {
    const int n = n0 + wn + ni * 16 + r;
    const float bv = bias[n];
#pragma unroll
    for (int mi = 0; mi < 4; ++mi) {
      const int mbase = m0 + wm + mi * 16 + qd * 4;
#pragma unroll
      for (int reg = 0; reg < 4; ++reg) {
        C[(size_t)(mbase + reg) * N + n] = acc[mi][ni][reg] + bv;
      }
    }
  }
}

// ---------------------------------------------------------------------------
// Fallback (small ws): register-staged GEMM, fused A-convert + B-dequant.
// ---------------------------------------------------------------------------
__global__ __launch_bounds__(256) void gemm_fused(
    const float* __restrict__ Af, const int* __restrict__ q,
    const float* __restrict__ scales, const float* __restrict__ bias,
    float* __restrict__ C, int M, int N, int K, int NB) {
  __shared__ bf16_t lsA[128 * 32];
  __shared__ bf16_t lsB[128 * 32];

  const int tid = threadIdx.x;
  const int lane = tid & 63;
  const int wave = tid >> 6;
  const int m0 = blockIdx.y * 128;
  const int n0 = blockIdx.x * 128;
  const int wm = (wave >> 1) * 64;
  const int wn = (wave & 1) * 64;
  const int r = lane & 15;
  const int qd = lane >> 4;

  const int e = tid * 16;
  const int row = e >> 5;
  const int col = e & 31;

  const float* gAf = Af + (size_t)(m0 + row) * K + col;
  const int* gQ = q + (size_t)(n0 + row) * K + col;
  const float* gS = scales + (size_t)(n0 + row) * NB;

  f32x4 acc[4][4] = {};

  for (int k0 = 0; k0 < K; k0 += 32) {
    bf16x8 a0, a1, b0, b1;
    {
      float4 f0 = *(const float4*)(gAf + k0);
      float4 f1 = *(const float4*)(gAf + k0 + 4);
      float4 f2 = *(const float4*)(gAf + k0 + 8);
      float4 f3 = *(const float4*)(gAf + k0 + 12);
      a0[0] = (bf16_t)f0.x; a0[1] = (bf16_t)f0.y; a0[2] = (bf16_t)f0.z; a0[3] = (bf16_t)f0.w;
      a0[4] = (bf16_t)f1.x; a0[5] = (bf16_t)f1.y; a0[6] = (bf16_t)f1.z; a0[7] = (bf16_t)f1.w;
      a1[0] = (bf16_t)f2.x; a1[1] = (bf16_t)f2.y; a1[2] = (bf16_t)f2.z; a1[3] = (bf16_t)f2.w;
      a1[4] = (bf16_t)f3.x; a1[5] = (bf16_t)f3.y; a1[6] = (bf16_t)f3.z; a1[7] = (bf16_t)f3.w;
    }
    {
      const float s = gS[k0 >> 5];
      int qv[16];
      *(int4*)&qv[0] = *(const int4*)(gQ + k0);
      *(int4*)&qv[4] = *(const int4*)(gQ + k0 + 4);
      *(int4*)&qv[8] = *(const int4*)(gQ + k0 + 8);
      *(int4*)&qv[12] = *(const int4*)(gQ + k0 + 12);
#pragma unroll
      for (int j = 0; j < 8; ++j) b0[j] = (bf16_t)((float)(qv[j] - QOFF) * s);
#pragma unroll
      for (int j = 0; j < 8; ++j)
        b1[j] = (bf16_t)((float)(qv[8 + j] - QOFF) * s);
    }

    __syncthreads();
    *(bf16x8*)&lsA[e] = a0;
    *(bf16x8*)&lsA[e + 8] = a1;
    *(bf16x8*)&lsB[e] = b0;
    *(bf16x8*)&lsB[e + 8] = b1;
    __syncthreads();

    bf16x8 af[4], bfv[4];
#pragma unroll
    for (int i = 0; i < 4; ++i) {
      af[i] = *(const bf16x8*)&lsA[(wm + i * 16 + r) * 32 + qd * 8];
      bfv[i] = *(const bf16x8*)&lsB[(wn + i * 16 + r) * 32 + qd * 8];
    }
#pragma unroll
    for (int mi = 0; mi < 4; ++mi)
#pragma unroll
      for (int ni = 0; ni < 4; ++ni)
        acc[mi][ni] = __builtin_amdgcn_mfma_f32_16x16x32_bf16(
            af[mi], bfv[ni], acc[mi][ni], 0, 0, 0);
  }

#pragma unroll
  for (int ni = 0; ni < 4; ++ni) {
    const int n = n0 + wn + ni * 16 + r;
    const float bv = bias[n];
#pragma unroll
    for (int mi = 0; mi < 4; ++mi) {
      const int mbase = m0 + wm + mi * 16 + qd * 4;
#pragma unroll
      for (int reg = 0; reg < 4; ++reg) {
        C[(size_t)(mbase + reg) * N + n] = acc[mi][ni][reg] + bv;
      }
    }
  }
}

// ---------------------------------------------------------------------------
extern "C" void kernel_launch(void* const* d_in, const int* in_sizes, int n_in,
                              void* d_out, int out_size, void* d_ws,
                              size_t ws_size, hipStream_t stream) {
  const float* x = (const float*)d_in[0];       // [M, K] fp32 (f16 upcast)
  const int* qw = (const int*)d_in[1];          // [O, K] int32
  const float* scales = (const float*)d_in[2];  // [O, NB] fp32
  const float* bias = (const float*)d_in[3];    // [O] fp32
  float* out = (float*)d_out;                   // [M, O] fp32

  const int O = in_sizes[3];       // 4096
  const int K = in_sizes[1] / O;   // 4096
  const int NB = in_sizes[2] / O;  // 128
  const int M = in_sizes[0] / K;   // 4096
  (void)n_in; (void)out_size;

  const size_t Wbytes = (size_t)O * K * sizeof(bf16_t);  // 32 MiB
  const size_t Xbytes = (size_t)M * K * sizeof(bf16_t);  // 32 MiB

  if (ws_size >= Wbytes + Xbytes) {
    bf16_t* W = (bf16_t*)d_ws;
    bf16_t* Xb = (bf16_t*)((char*)d_ws + Wbytes);
    const int nDeq = (int)((size_t)O * K / 2048);
    const int nCvt = (int)((size_t)M * K / 2048);
    prep_kernel<<<nDeq + nCvt, 256, 0, stream>>>(qw, scales, x, W, Xb, K, NB,
                                                 nDeq);
    if ((M % 256) == 0 && (O % 256) == 0 && (K % 128) == 0) {
      const int nwg = (M / 256) * (O / 256);
      gemm_8ph<<<nwg, 512, 0, stream>>>(Xb, W, bias, out, M, O, K);
    } else {
      dim3 grid(O / 128, M / 128);
      gemm_db<<<grid, 256, 0, stream>>>(Xb, W, bias, out, M, O, K);
    }
  } else {
    dim3 grid(O / 128, M / 128);
    gemm_fused<<<grid, 256, 0, stream>>>(x, qw, scales, bias, out, M, O, K,
                                         NB);
  }
}